// Round 3
// 2959.874 us; speedup vs baseline: 1.6894x; 1.6894x over previous
//
#include <hip/hip_runtime.h>

// Problem constants (match reference)
#define CDIM 1024
#define TLEN 2048
#define BATCH 2
#define NTOK 4096      // BATCH*TLEN
#define NHEAD 16
#define HDIM 64
#define NEXP 8
#define HID 4096
#define NSLOT 8192     // NTOK * TOPK

typedef __attribute__((ext_vector_type(8))) short bf16x8;
typedef __attribute__((ext_vector_type(4))) float f32x4;

__device__ __forceinline__ float bf2f(unsigned short u) {
  return __uint_as_float(((unsigned int)u) << 16);
}
__device__ __forceinline__ unsigned short f2bf(float f) {
  unsigned int x = __float_as_uint(f);
  unsigned int r = (x + 0x7fffu + ((x >> 16) & 1u)) >> 16;
  return (unsigned short)r;
}
__device__ __forceinline__ void f4a(float4 v, float* a) {
  a[0] = v.x; a[1] = v.y; a[2] = v.z; a[3] = v.w;
}
// Direct global->LDS DMA, 16B per lane. LDS dest is wave-uniform base + lane*16.
__device__ __forceinline__ void gload_lds16(const unsigned short* g, unsigned short* l) {
  __builtin_amdgcn_global_load_lds((const __attribute__((address_space(1))) void*)g,
                                   (__attribute__((address_space(3))) void*)l, 16, 0, 0);
}

// ---------------- RMSNorm -> fp32 out (attention path: must stay fp32) -----
__global__ __launch_bounds__(256) void rmsnorm_f32_k(const float* __restrict__ in,
                                                     const float* __restrict__ w,
                                                     float* __restrict__ out) {
  int row = blockIdx.x;
  int tid = threadIdx.x;  // 256 threads, 4 floats each = 1024
  float4 a = ((const float4*)(in + (size_t)row * CDIM))[tid];
  float ss = a.x * a.x + a.y * a.y + a.z * a.z + a.w * a.w;
#pragma unroll
  for (int off = 32; off > 0; off >>= 1) ss += __shfl_xor(ss, off);
  __shared__ float sred[4];
  if ((tid & 63) == 0) sred[tid >> 6] = ss;
  __syncthreads();
  float tot = sred[0] + sred[1] + sred[2] + sred[3];
  float inv = rsqrtf(tot * (1.0f / CDIM) + 1e-8f);
  float4 wv = ((const float4*)w)[tid];
  float4 o;
  o.x = a.x * inv * wv.x; o.y = a.y * inv * wv.y;
  o.z = a.z * inv * wv.z; o.w = a.w * inv * wv.w;
  ((float4*)(out + (size_t)row * CDIM))[tid] = o;
}

// ---------------- RMSNorm -> bf16 out (MoE A-operand) -----------------------
__global__ __launch_bounds__(256) void rmsnorm_bf16_k(const float* __restrict__ in,
                                                      const float* __restrict__ w,
                                                      unsigned short* __restrict__ out) {
  int row = blockIdx.x;
  int tid = threadIdx.x;
  float4 a = ((const float4*)(in + (size_t)row * CDIM))[tid];
  float ss = a.x * a.x + a.y * a.y + a.z * a.z + a.w * a.w;
#pragma unroll
  for (int off = 32; off > 0; off >>= 1) ss += __shfl_xor(ss, off);
  __shared__ float sred[4];
  if ((tid & 63) == 0) sred[tid >> 6] = ss;
  __syncthreads();
  float tot = sred[0] + sred[1] + sred[2] + sred[3];
  float inv = rsqrtf(tot * (1.0f / CDIM) + 1e-8f);
  float4 wv = ((const float4*)w)[tid];
  ushort4 o;
  o.x = f2bf(a.x * inv * wv.x); o.y = f2bf(a.y * inv * wv.y);
  o.z = f2bf(a.z * inv * wv.z); o.w = f2bf(a.w * inv * wv.w);
  ((ushort4*)(out + (size_t)row * CDIM))[tid] = o;
}

// ---------------- fp32 [R][Cn] -> bf16 [Cn][R] transpose-convert ------------
__global__ __launch_bounds__(256) void convT_k(const float* __restrict__ src,
                                               unsigned short* __restrict__ dst,
                                               int R, int Cn) {
  const float* s = src + (size_t)blockIdx.z * R * Cn;
  unsigned short* d = dst + (size_t)blockIdx.z * R * Cn;
  __shared__ unsigned short tile[64][65];
  int r0 = blockIdx.y * 64, c0 = blockIdx.x * 64;
  int t = threadIdx.x;
  int lr = t >> 2, lc = (t & 3) * 16;
  const float* sp = s + (size_t)(r0 + lr) * Cn + c0 + lc;
#pragma unroll
  for (int u = 0; u < 4; u++) {
    float4 v = *(const float4*)(sp + 4 * u);
    tile[lr][lc + 4 * u + 0] = f2bf(v.x);
    tile[lr][lc + 4 * u + 1] = f2bf(v.y);
    tile[lr][lc + 4 * u + 2] = f2bf(v.z);
    tile[lr][lc + 4 * u + 3] = f2bf(v.w);
  }
  __syncthreads();
  int cc = t >> 2, rr = (t & 3) * 16;
  __attribute__((aligned(16))) unsigned short tmp[16];
#pragma unroll
  for (int u = 0; u < 16; u++) tmp[u] = tile[rr + u][cc];
  unsigned short* dp = d + (size_t)(c0 + cc) * R + r0 + rr;
  *(uint4*)dp = *(const uint4*)tmp;
  *(uint4*)(dp + 8) = *(const uint4*)(tmp + 8);
}

// ---------------- fp32 GEMM (attention path): out = A@W + bias (+resid) ----
// 64x64 tile, 256 threads, 4x4 per thread. Harness-verified baseline kernel.
__global__ __launch_bounds__(256) void gemm_bias_k(
    const float* __restrict__ A, const float* __restrict__ W,
    const float* __restrict__ bias, const float* __restrict__ resid,
    float* __restrict__ out, int Kdim, int Nd) {
  __shared__ float As[16][68];  // As[k][m]
  __shared__ float Bs[16][68];  // Bs[k][n]
  int t = threadIdx.x;
  int tx = t & 15, ty = t >> 4;
  int m0 = blockIdx.y * 64, n0 = blockIdx.x * 64;
  int arow = t >> 2, ak = (t & 3) * 4;
  int brow = t >> 4, bc = (t & 15) * 4;
  float acc[4][4] = {};
  for (int k0 = 0; k0 < Kdim; k0 += 16) {
    float4 av = *(const float4*)(A + (size_t)(m0 + arow) * Kdim + k0 + ak);
    float4 bv = *(const float4*)(W + (size_t)(k0 + brow) * Nd + n0 + bc);
    __syncthreads();
    As[ak + 0][arow] = av.x; As[ak + 1][arow] = av.y;
    As[ak + 2][arow] = av.z; As[ak + 3][arow] = av.w;
    *(float4*)&Bs[brow][bc] = bv;
    __syncthreads();
#pragma unroll
    for (int kk = 0; kk < 16; kk++) {
      float as[4], bs[4];
      f4a(*(const float4*)&As[kk][ty * 4], as);
      f4a(*(const float4*)&Bs[kk][tx * 4], bs);
#pragma unroll
      for (int i = 0; i < 4; i++)
#pragma unroll
        for (int j = 0; j < 4; j++) acc[i][j] += as[i] * bs[j];
    }
  }
#pragma unroll
  for (int i = 0; i < 4; i++) {
    int m = m0 + ty * 4 + i;
#pragma unroll
    for (int j = 0; j < 4; j++) {
      int n = n0 + tx * 4 + j;
      float v = acc[i][j] + bias[n];
      if (resid) v += resid[(size_t)m * Nd + n];
      out[(size_t)m * Nd + n] = v;
    }
  }
}

// ---------------- Flash attention with ALiBi (fp32 in/out) ------------------
__global__ __launch_bounds__(256) void attn_k(const float* __restrict__ q,
                                              const float* __restrict__ kv,
                                              float* __restrict__ y) {
  int qt = blockIdx.x, h = blockIdx.y, b = blockIdx.z;
  __shared__ float Qs[64][68];
  __shared__ float KPs[64][68];  // K tile, then reused for P
  __shared__ float Vs[64][68];
  int t = threadIdx.x, tx = t & 15, ty = t >> 4;
  int lrow = t >> 4, lcol = (t & 15) * 4;
  size_t qbase = (size_t)b * TLEN + (size_t)qt * 64;
#pragma unroll
  for (int it = 0; it < 4; it++) {
    int row = lrow + it * 16;
    *(float4*)&Qs[row][lcol] =
        *(const float4*)(q + (qbase + row) * CDIM + h * HDIM + lcol);
  }
  float m_i[4], l_i[4], o[4][4];
#pragma unroll
  for (int i = 0; i < 4; i++) {
    m_i[i] = -1e30f; l_i[i] = 0.f;
#pragma unroll
    for (int j = 0; j < 4; j++) o[i][j] = 0.f;
  }
  float slope = (float)(h + 1) * (1.0f / NHEAD);
  for (int kt = 0; kt <= qt; kt++) {
    size_t kbase = (size_t)b * TLEN + (size_t)kt * 64;
    float4 kreg[4], vreg[4];
#pragma unroll
    for (int it = 0; it < 4; it++) {
      int row = lrow + it * 16;
      kreg[it] = *(const float4*)(kv + (kbase + row) * (2 * CDIM) + h * HDIM + lcol);
      vreg[it] = *(const float4*)(kv + (kbase + row) * (2 * CDIM) + CDIM + h * HDIM + lcol);
    }
    __syncthreads();
#pragma unroll
    for (int it = 0; it < 4; it++) {
      int row = lrow + it * 16;
      *(float4*)&KPs[row][lcol] = kreg[it];
      *(float4*)&Vs[row][lcol] = vreg[it];
    }
    __syncthreads();
    float s[4][4] = {};
    for (int d = 0; d < HDIM; d += 4) {
      float qv[4][4], kvv[4][4];
#pragma unroll
      for (int i = 0; i < 4; i++) f4a(*(const float4*)&Qs[ty * 4 + i][d], qv[i]);
#pragma unroll
      for (int j = 0; j < 4; j++) f4a(*(const float4*)&KPs[tx * 4 + j][d], kvv[j]);
#pragma unroll
      for (int i = 0; i < 4; i++)
#pragma unroll
        for (int j = 0; j < 4; j++)
          s[i][j] += qv[i][0] * kvv[j][0] + qv[i][1] * kvv[j][1] +
                     qv[i][2] * kvv[j][2] + qv[i][3] * kvv[j][3];
    }
#pragma unroll
    for (int i = 0; i < 4; i++) {
      int qg = qt * 64 + ty * 4 + i;
      float sv[4], rowm = -1e30f;
#pragma unroll
      for (int j = 0; j < 4; j++) {
        int kg = kt * 64 + tx * 4 + j;
        float v = s[i][j] * 0.125f + slope * (float)(kg - qg);
        v = (kg <= qg) ? v : -1e30f;
        sv[j] = v;
        rowm = fmaxf(rowm, v);
      }
#pragma unroll
      for (int off = 1; off < 16; off <<= 1) rowm = fmaxf(rowm, __shfl_xor(rowm, off));
      float newm = fmaxf(m_i[i], rowm);
      float alpha = __expf(m_i[i] - newm);
      float rs = 0.f;
#pragma unroll
      for (int j = 0; j < 4; j++) {
        float p = __expf(sv[j] - newm);
        s[i][j] = p;
        rs += p;
      }
#pragma unroll
      for (int off = 1; off < 16; off <<= 1) rs += __shfl_xor(rs, off);
      l_i[i] = l_i[i] * alpha + rs;
      m_i[i] = newm;
#pragma unroll
      for (int j = 0; j < 4; j++) o[i][j] *= alpha;
    }
    __syncthreads();
#pragma unroll
    for (int i = 0; i < 4; i++)
#pragma unroll
      for (int j = 0; j < 4; j++) KPs[ty * 4 + i][tx * 4 + j] = s[i][j];
    __syncthreads();
    for (int kk = 0; kk < 64; kk += 4) {
      float pr[4][4], vv[4][4];
#pragma unroll
      for (int i = 0; i < 4; i++) f4a(*(const float4*)&KPs[ty * 4 + i][kk], pr[i]);
#pragma unroll
      for (int u = 0; u < 4; u++) f4a(*(const float4*)&Vs[kk + u][tx * 4], vv[u]);
#pragma unroll
      for (int i = 0; i < 4; i++)
#pragma unroll
        for (int j = 0; j < 4; j++)
          o[i][j] += pr[i][0] * vv[0][j] + pr[i][1] * vv[1][j] +
                     pr[i][2] * vv[2][j] + pr[i][3] * vv[3][j];
    }
  }
#pragma unroll
  for (int i = 0; i < 4; i++) {
    float invl = 1.0f / l_i[i];
    size_t row = qbase + ty * 4 + i;
#pragma unroll
    for (int j = 0; j < 4; j++)
      y[row * CDIM + h * HDIM + tx * 4 + j] = o[i][j] * invl;
  }
}

// ---------------- Router: fp32 rmsnorm + logits from post-attn residual ----
__global__ void zero_cnt_k(int* cnt) {
  if (threadIdx.x < NEXP) cnt[threadIdx.x] = 0;
}

__global__ __launch_bounds__(64) void router_k(const float* __restrict__ xr,
                                               const float* __restrict__ fnw,
                                               const float* __restrict__ rw,
                                               int* __restrict__ sel_idx,
                                               float* __restrict__ sel_w,
                                               int* __restrict__ cnt) {
  int tok = blockIdx.x;
  int lane = threadIdx.x;  // 64
  const float* row = xr + (size_t)tok * CDIM;
  float4 v[4];
  float ss = 0.f;
#pragma unroll
  for (int u = 0; u < 4; u++) {
    v[u] = ((const float4*)row)[lane + 64 * u];
    ss += v[u].x * v[u].x + v[u].y * v[u].y + v[u].z * v[u].z + v[u].w * v[u].w;
  }
#pragma unroll
  for (int off = 32; off > 0; off >>= 1) ss += __shfl_xor(ss, off);
  float inv = rsqrtf(ss * (1.0f / CDIM) + 1e-8f);
  float acc[NEXP] = {};
#pragma unroll
  for (int u = 0; u < 4; u++) {
    int c0 = (lane + 64 * u) * 4;
    float hv[4];
    f4a(v[u], hv);
#pragma unroll
    for (int j = 0; j < 4; j++) {
      float h = hv[j] * inv * fnw[c0 + j];
      const float* r = rw + (size_t)(c0 + j) * NEXP;
#pragma unroll
      for (int e = 0; e < NEXP; e++) acc[e] += h * r[e];
    }
  }
#pragma unroll
  for (int e = 0; e < NEXP; e++)
#pragma unroll
    for (int off = 32; off > 0; off >>= 1) acc[e] += __shfl_xor(acc[e], off);
  if (lane == 0) {
    int i0 = 0; float l0 = acc[0];
    for (int e = 1; e < NEXP; e++) if (acc[e] > l0) { l0 = acc[e]; i0 = e; }
    int i1 = -1; float l1 = -1e30f;
    for (int e = 0; e < NEXP; e++)
      if (e != i0 && acc[e] > l1) { l1 = acc[e]; i1 = e; }
    float w0 = 1.f / (1.f + __expf(l1 - l0));
    sel_idx[2 * tok] = i0; sel_idx[2 * tok + 1] = i1;
    sel_w[2 * tok] = w0;   sel_w[2 * tok + 1] = 1.f - w0;
    atomicAdd(&cnt[i0], 1);
    atomicAdd(&cnt[i1], 1);
  }
}

__global__ void scan_k(const int* __restrict__ cnt, int* __restrict__ eoff,
                       int* __restrict__ cursor) {
  if (threadIdx.x == 0) {
    int s = 0;
    for (int e = 0; e < NEXP; e++) { eoff[e] = s; cursor[e] = s; s += cnt[e]; }
    eoff[NEXP] = s;
  }
}

__global__ __launch_bounds__(256) void gather_k(const int* __restrict__ sel_idx,
                                                const float* __restrict__ sel_w,
                                                int* __restrict__ cursor,
                                                int* __restrict__ gtok,
                                                float* __restrict__ gwv) {
  int t = blockIdx.x * blockDim.x + threadIdx.x;
  if (t >= NTOK) return;
#pragma unroll
  for (int k = 0; k < 2; k++) {
    int e = sel_idx[2 * t + k];
    int p = atomicAdd(&cursor[e], 1);
    gtok[p] = t;
    gwv[p] = sel_w[2 * t + k];
  }
}

// ---------------- MoE GEMM1 (MFMA): mid = bf16( silu(h2@gate) * (h2@up) ) --
// 128x128 tile, BK=64, 4 waves, 16x16x32 bf16 MFMA, global_load_lds staging
// with XOR-swizzled source (slot^=row&7) for conflict-free ds_read_b128.
__global__ __launch_bounds__(256) void moe_g1_k(
    const unsigned short* __restrict__ h2b, const unsigned short* __restrict__ gT,
    const unsigned short* __restrict__ uT, const int* __restrict__ cnt,
    const int* __restrict__ eoff, const int* __restrict__ gtok,
    unsigned short* __restrict__ mid) {
  int e = blockIdx.z, rt = blockIdx.y, ht = blockIdx.x;
  int ne = cnt[e];
  if (rt * 128 >= ne) return;
  int base = eoff[e];
  __shared__ __attribute__((aligned(16))) unsigned short As[128 * 64];
  __shared__ __attribute__((aligned(16))) unsigned short B1s[128 * 64];
  __shared__ __attribute__((aligned(16))) unsigned short B2s[128 * 64];
  __shared__ int toks[128];
  int t = threadIdx.x;
  if (t < 128) {
    int r = rt * 128 + t;
    toks[t] = (r < ne) ? gtok[base + r] : 0;  // pad rows read row 0 (discarded)
  }
  __syncthreads();
  int w = t >> 6, l = t & 63, l16 = l & 15, lg = l >> 4;
  int wm = (w >> 1) * 64, wn = (w & 1) * 64;
  int srow = t >> 3, sslot = t & 7;
  const unsigned short* G = gT + (size_t)e * CDIM * HID;  // [HID][CDIM]
  const unsigned short* U = uT + (size_t)e * CDIM * HID;
  int n0 = ht * 128;
  int arows[4];
#pragma unroll
  for (int i = 0; i < 4; i++) arows[i] = toks[i * 32 + srow];
  f32x4 acc1[4][4] = {}, acc2[4][4] = {};
  for (int k0 = 0; k0 < CDIM; k0 += 64) {
    __syncthreads();
#pragma unroll
    for (int i = 0; i < 4; i++) {
      int r = i * 32 + srow;
      int sl = sslot ^ (r & 7);
      gload_lds16(h2b + (size_t)arows[i] * CDIM + k0 + sl * 8, As + i * 2048 + w * 512);
      gload_lds16(G + (size_t)(n0 + r) * CDIM + k0 + sl * 8, B1s + i * 2048 + w * 512);
      gload_lds16(U + (size_t)(n0 + r) * CDIM + k0 + sl * 8, B2s + i * 2048 + w * 512);
    }
    __syncthreads();
#pragma unroll
    for (int ks = 0; ks < 2; ks++) {
      bf16x8 af[4], b1[4], b2[4];
#pragma unroll
      for (int x = 0; x < 4; x++) {
        int ar = wm + x * 16 + l16;
        int br = wn + x * 16 + l16;
        int aof = ar * 64 + (((ks * 4 + lg) ^ (ar & 7)) << 3);
        int bof = br * 64 + (((ks * 4 + lg) ^ (br & 7)) << 3);
        af[x] = *(const bf16x8*)&As[aof];
        b1[x] = *(const bf16x8*)&B1s[bof];
        b2[x] = *(const bf16x8*)&B2s[bof];
      }
#pragma unroll
      for (int mi = 0; mi < 4; mi++)
#pragma unroll
        for (int nj = 0; nj < 4; nj++) {
          acc1[mi][nj] = __builtin_amdgcn_mfma_f32_16x16x32_bf16(af[mi], b1[nj], acc1[mi][nj], 0, 0, 0);
          acc2[mi][nj] = __builtin_amdgcn_mfma_f32_16x16x32_bf16(af[mi], b2[nj], acc2[mi][nj], 0, 0, 0);
        }
    }
  }
#pragma unroll
  for (int mi = 0; mi < 4; mi++)
#pragma unroll
    for (int rr = 0; rr < 4; rr++) {
      int rloc = wm + mi * 16 + lg * 4 + rr;
      int r = rt * 128 + rloc;
      if (r < ne) {
        size_t slot = (size_t)base + r;
#pragma unroll
        for (int nj = 0; nj < 4; nj++) {
          float g = acc1[mi][nj][rr], u = acc2[mi][nj][rr];
          float val = g / (1.f + __expf(-g)) * u;  // silu(g)*u
          mid[slot * HID + n0 + wn + nj * 16 + l16] = f2bf(val);
        }
      }
    }
}

// ---------------- MoE GEMM2 (MFMA): out += w * (mid @ down_e) --------------
__global__ __launch_bounds__(256) void moe_g2_k(
    const unsigned short* __restrict__ mid, const unsigned short* __restrict__ dT,
    const int* __restrict__ cnt, const int* __restrict__ eoff,
    const int* __restrict__ gtok, const float* __restrict__ gwv,
    float* __restrict__ out) {
  int e = blockIdx.z, rt = blockIdx.y, ct = blockIdx.x;
  int ne = cnt[e];
  if (rt * 128 >= ne) return;
  int base = eoff[e];
  __shared__ __attribute__((aligned(16))) unsigned short As[128 * 64];
  __shared__ __attribute__((aligned(16))) unsigned short Bs[128 * 64];
  int t = threadIdx.x;
  int w = t >> 6, l = t & 63, l16 = l & 15, lg = l >> 4;
  int wm = (w >> 1) * 64, wn = (w & 1) * 64;
  int srow = t >> 3, sslot = t & 7;
  const unsigned short* D = dT + (size_t)e * HID * CDIM;  // [CDIM][HID]
  int n0 = ct * 128;
  int aslots[4];
#pragma unroll
  for (int i = 0; i < 4; i++) {
    int sidx = base + rt * 128 + i * 32 + srow;
    aslots[i] = (sidx < NSLOT) ? sidx : (NSLOT - 1);  // pad rows discarded
  }
  f32x4 acc[4][4] = {};
  for (int k0 = 0; k0 < HID; k0 += 64) {
    __syncthreads();
#pragma unroll
    for (int i = 0; i < 4; i++) {
      int r = i * 32 + srow;
      int sl = sslot ^ (r & 7);
      gload_lds16(mid + (size_t)aslots[i] * HID + k0 + sl * 8, As + i * 2048 + w * 512);
      gload_lds16(D + (size_t)(n0 + r) * HID + k0 + sl * 8, Bs + i * 2048 + w * 512);
    }
    __syncthreads();
#pragma unroll
    for (int ks = 0; ks < 2; ks++) {
      bf16x8 af[4], bfr[4];
#pragma unroll
      for (int x = 0; x < 4; x++) {
        int ar = wm + x * 16 + l16;
        int br = wn + x * 16 + l16;
        af[x]  = *(const bf16x8*)&As[ar * 64 + (((ks * 4 + lg) ^ (ar & 7)) << 3)];
        bfr[x] = *(const bf16x8*)&Bs[br * 64 + (((ks * 4 + lg) ^ (br & 7)) << 3)];
      }
#pragma unroll
      for (int mi = 0; mi < 4; mi++)
#pragma unroll
        for (int nj = 0; nj < 4; nj++)
          acc[mi][nj] = __builtin_amdgcn_mfma_f32_16x16x32_bf16(af[mi], bfr[nj], acc[mi][nj], 0, 0, 0);
    }
  }
#pragma unroll
  for (int mi = 0; mi < 4; mi++)
#pragma unroll
    for (int rr = 0; rr < 4; rr++) {
      int r = rt * 128 + wm + mi * 16 + lg * 4 + rr;
      if (r < ne) {
        int tok = gtok[base + r];
        float wv = gwv[base + r];
#pragma unroll
        for (int nj = 0; nj < 4; nj++)
          atomicAdd(&out[(size_t)tok * CDIM + n0 + wn + nj * 16 + l16],
                    wv * acc[mi][nj][rr]);
      }
    }
}

// ---------------------------------------------------------------------------
extern "C" void kernel_launch(void* const* d_in, const int* in_sizes, int n_in,
                              void* d_out, int out_size, void* d_ws, size_t ws_size,
                              hipStream_t stream) {
  (void)in_sizes; (void)n_in; (void)out_size; (void)ws_size;
  const float* x   = (const float*)d_in[0];
  const float* anw = (const float*)d_in[1];
  const float* fnw = (const float*)d_in[2];
  const float* qw  = (const float*)d_in[3];
  const float* qb  = (const float*)d_in[4];
  const float* kvw = (const float*)d_in[5];
  const float* kvb = (const float*)d_in[6];
  const float* ow  = (const float*)d_in[7];
  const float* ob  = (const float*)d_in[8];
  const float* rw  = (const float*)d_in[9];
  const float* gw  = (const float*)d_in[10];
  const float* uw  = (const float*)d_in[11];
  const float* dw  = (const float*)d_in[12];
  float* out = (float*)d_out;

  // Workspace layout (265 MiB; 273 MiB proven addressable in r0/r1):
  //   [0,32K)    sel_idx int[8192]
  //   [32K,64K)  sel_w   float[8192]
  //   [64K,..)   cnt[16]/eoff/cursor
  //   [96K,128K) gtok int[8192]
  //   [128K,..)  gwv float[8192]
  //   [1M,17M)   h1 f32, then yf f32 (h1 dead after kv GEMM)
  //   [17M,33M)  qf f32
  //   [33M,65M)  kvf f32
  //   mid bf16 [8192][4096] aliases [1M,65M) (all f32 bufs dead pre-MoE)
  //   [65M,73M)  h2b bf16
  //   [73M,137M)  gT bf16 [8][4096][1024]
  //   [137M,201M) uT bf16 [8][4096][1024]
  //   [201M,265M) dT bf16 [8][1024][4096]
  char* ws = (char*)d_ws;
  int*   sel_idx = (int*)(ws);
  float* sel_w   = (float*)(ws + (32 << 10));
  int*   cnt     = (int*)(ws + (64 << 10));
  int*   eoff    = cnt + 16;
  int*   cursor  = cnt + 32;
  int*   gtok    = (int*)(ws + (96 << 10));
  float* gwv     = (float*)(ws + (128 << 10));
  float* h1f = (float*)(ws + ((size_t)1 << 20));
  float* yf  = h1f;  // alias: h1 dead before attention writes y
  float* qf  = (float*)(ws + ((size_t)17 << 20));
  float* kvf = (float*)(ws + ((size_t)33 << 20));
  unsigned short* mid = (unsigned short*)(ws + ((size_t)1 << 20));
  unsigned short* h2b = (unsigned short*)(ws + ((size_t)65 << 20));
  unsigned short* gT = (unsigned short*)(ws + ((size_t)73 << 20));
  unsigned short* uT = (unsigned short*)(ws + ((size_t)137 << 20));
  unsigned short* dT = (unsigned short*)(ws + ((size_t)201 << 20));

  zero_cnt_k<<<1, 64, 0, stream>>>(cnt);
  // MoE weight convert+transpose to bf16 [N][K]
  convT_k<<<dim3(64, 16, NEXP), 256, 0, stream>>>(gw, gT, CDIM, HID);
  convT_k<<<dim3(64, 16, NEXP), 256, 0, stream>>>(uw, uT, CDIM, HID);
  convT_k<<<dim3(16, 64, NEXP), 256, 0, stream>>>(dw, dT, HID, CDIM);
  // h1 = rmsnorm(x) (fp32 — attention path must match fp32 reference)
  rmsnorm_f32_k<<<NTOK, 256, 0, stream>>>(x, anw, h1f);
  // q = h1@qw + qb ; kv = h1@kvw + kvb   (fp32)
  gemm_bias_k<<<dim3(16, 64), 256, 0, stream>>>(h1f, qw, qb, nullptr, qf, CDIM, CDIM);
  gemm_bias_k<<<dim3(32, 64), 256, 0, stream>>>(h1f, kvw, kvb, nullptr, kvf, CDIM, 2 * CDIM);
  // y = attention(q, k, v)  (fp32; yf aliases h1 which is now dead)
  attn_k<<<dim3(32, NHEAD, BATCH), 256, 0, stream>>>(qf, kvf, yf);
  // out = x + y@ow + ob  (fp32)
  gemm_bias_k<<<dim3(16, 64), 256, 0, stream>>>(yf, ow, ob, x, out, CDIM, CDIM);
  // h2 = rmsnorm(out) (bf16, MoE A-operand)
  rmsnorm_bf16_k<<<NTOK, 256, 0, stream>>>(out, fnw, h2b);
  // routing: fp32-exact logits from post-attn residual
  router_k<<<NTOK, 64, 0, stream>>>(out, fnw, rw, sel_idx, sel_w, cnt);
  scan_k<<<1, 64, 0, stream>>>(cnt, eoff, cursor);
  gather_k<<<16, 256, 0, stream>>>(sel_idx, sel_w, cursor, gtok, gwv);
  // MoE (bf16 MFMA — post-routing, continuous error only)
  moe_g1_k<<<dim3(HID / 128, 64, NEXP), 256, 0, stream>>>(h2b, gT, uT, cnt, eoff, gtok, mid);
  moe_g2_k<<<dim3(CDIM / 128, 64, NEXP), 256, 0, stream>>>(mid, dT, cnt, eoff, gtok, gwv, out);
}

// Round 4
// 1776.700 us; speedup vs baseline: 2.8145x; 1.6659x over previous
//
#include <hip/hip_runtime.h>

// Problem constants (match reference)
#define CDIM 1024
#define TLEN 2048
#define BATCH 2
#define NTOK 4096      // BATCH*TLEN
#define NHEAD 16
#define HDIM 64
#define NEXP 8
#define HID 4096
#define NSLOT 8192     // NTOK * TOPK

typedef __attribute__((ext_vector_type(8))) short bf16x8;
typedef __attribute__((ext_vector_type(4))) float f32x4;

__device__ __forceinline__ float bf2f(unsigned short u) {
  return __uint_as_float(((unsigned int)u) << 16);
}
__device__ __forceinline__ unsigned short f2bf(float f) {
  unsigned int x = __float_as_uint(f);
  unsigned int r = (x + 0x7fffu + ((x >> 16) & 1u)) >> 16;
  return (unsigned short)r;
}
__device__ __forceinline__ void f4a(float4 v, float* a) {
  a[0] = v.x; a[1] = v.y; a[2] = v.z; a[3] = v.w;
}
// Direct global->LDS DMA, 16B per lane. LDS dest is wave-uniform base + lane*16.
__device__ __forceinline__ void gload_lds16(const unsigned short* g, unsigned short* l) {
  __builtin_amdgcn_global_load_lds((const __attribute__((address_space(1))) void*)g,
                                   (__attribute__((address_space(3))) void*)l, 16, 0, 0);
}

// ---------------- RMSNorm -> fp32 out (attention path: must stay fp32) -----
__global__ __launch_bounds__(256) void rmsnorm_f32_k(const float* __restrict__ in,
                                                     const float* __restrict__ w,
                                                     float* __restrict__ out) {
  int row = blockIdx.x;
  int tid = threadIdx.x;  // 256 threads, 4 floats each = 1024
  float4 a = ((const float4*)(in + (size_t)row * CDIM))[tid];
  float ss = a.x * a.x + a.y * a.y + a.z * a.z + a.w * a.w;
#pragma unroll
  for (int off = 32; off > 0; off >>= 1) ss += __shfl_xor(ss, off);
  __shared__ float sred[4];
  if ((tid & 63) == 0) sred[tid >> 6] = ss;
  __syncthreads();
  float tot = sred[0] + sred[1] + sred[2] + sred[3];
  float inv = rsqrtf(tot * (1.0f / CDIM) + 1e-8f);
  float4 wv = ((const float4*)w)[tid];
  float4 o;
  o.x = a.x * inv * wv.x; o.y = a.y * inv * wv.y;
  o.z = a.z * inv * wv.z; o.w = a.w * inv * wv.w;
  ((float4*)(out + (size_t)row * CDIM))[tid] = o;
}

// ---------------- RMSNorm -> bf16 out (MoE A-operand) -----------------------
__global__ __launch_bounds__(256) void rmsnorm_bf16_k(const float* __restrict__ in,
                                                      const float* __restrict__ w,
                                                      unsigned short* __restrict__ out) {
  int row = blockIdx.x;
  int tid = threadIdx.x;
  float4 a = ((const float4*)(in + (size_t)row * CDIM))[tid];
  float ss = a.x * a.x + a.y * a.y + a.z * a.z + a.w * a.w;
#pragma unroll
  for (int off = 32; off > 0; off >>= 1) ss += __shfl_xor(ss, off);
  __shared__ float sred[4];
  if ((tid & 63) == 0) sred[tid >> 6] = ss;
  __syncthreads();
  float tot = sred[0] + sred[1] + sred[2] + sred[3];
  float inv = rsqrtf(tot * (1.0f / CDIM) + 1e-8f);
  float4 wv = ((const float4*)w)[tid];
  ushort4 o;
  o.x = f2bf(a.x * inv * wv.x); o.y = f2bf(a.y * inv * wv.y);
  o.z = f2bf(a.z * inv * wv.z); o.w = f2bf(a.w * inv * wv.w);
  ((ushort4*)(out + (size_t)row * CDIM))[tid] = o;
}

// ---------------- fp32 [R][Cn] -> bf16 [Cn][R] transpose-convert ------------
__global__ __launch_bounds__(256) void convT_k(const float* __restrict__ src,
                                               unsigned short* __restrict__ dst,
                                               int R, int Cn) {
  const float* s = src + (size_t)blockIdx.z * R * Cn;
  unsigned short* d = dst + (size_t)blockIdx.z * R * Cn;
  __shared__ unsigned short tile[64][65];
  int r0 = blockIdx.y * 64, c0 = blockIdx.x * 64;
  int t = threadIdx.x;
  int lr = t >> 2, lc = (t & 3) * 16;
  const float* sp = s + (size_t)(r0 + lr) * Cn + c0 + lc;
#pragma unroll
  for (int u = 0; u < 4; u++) {
    float4 v = *(const float4*)(sp + 4 * u);
    tile[lr][lc + 4 * u + 0] = f2bf(v.x);
    tile[lr][lc + 4 * u + 1] = f2bf(v.y);
    tile[lr][lc + 4 * u + 2] = f2bf(v.z);
    tile[lr][lc + 4 * u + 3] = f2bf(v.w);
  }
  __syncthreads();
  int cc = t >> 2, rr = (t & 3) * 16;
  __attribute__((aligned(16))) unsigned short tmp[16];
#pragma unroll
  for (int u = 0; u < 16; u++) tmp[u] = tile[rr + u][cc];
  unsigned short* dp = d + (size_t)(c0 + cc) * R + r0 + rr;
  *(uint4*)dp = *(const uint4*)tmp;
  *(uint4*)(dp + 8) = *(const uint4*)(tmp + 8);
}

// ---------------- fp32 GEMM (attention path): out = A@W + bias (+resid) ----
__global__ __launch_bounds__(256) void gemm_bias_k(
    const float* __restrict__ A, const float* __restrict__ W,
    const float* __restrict__ bias, const float* __restrict__ resid,
    float* __restrict__ out, int Kdim, int Nd) {
  __shared__ float As[16][68];  // As[k][m]
  __shared__ float Bs[16][68];  // Bs[k][n]
  int t = threadIdx.x;
  int tx = t & 15, ty = t >> 4;
  int m0 = blockIdx.y * 64, n0 = blockIdx.x * 64;
  int arow = t >> 2, ak = (t & 3) * 4;
  int brow = t >> 4, bc = (t & 15) * 4;
  float acc[4][4] = {};
  for (int k0 = 0; k0 < Kdim; k0 += 16) {
    float4 av = *(const float4*)(A + (size_t)(m0 + arow) * Kdim + k0 + ak);
    float4 bv = *(const float4*)(W + (size_t)(k0 + brow) * Nd + n0 + bc);
    __syncthreads();
    As[ak + 0][arow] = av.x; As[ak + 1][arow] = av.y;
    As[ak + 2][arow] = av.z; As[ak + 3][arow] = av.w;
    *(float4*)&Bs[brow][bc] = bv;
    __syncthreads();
#pragma unroll
    for (int kk = 0; kk < 16; kk++) {
      float as[4], bs[4];
      f4a(*(const float4*)&As[kk][ty * 4], as);
      f4a(*(const float4*)&Bs[kk][tx * 4], bs);
#pragma unroll
      for (int i = 0; i < 4; i++)
#pragma unroll
        for (int j = 0; j < 4; j++) acc[i][j] += as[i] * bs[j];
    }
  }
#pragma unroll
  for (int i = 0; i < 4; i++) {
    int m = m0 + ty * 4 + i;
#pragma unroll
    for (int j = 0; j < 4; j++) {
      int n = n0 + tx * 4 + j;
      float v = acc[i][j] + bias[n];
      if (resid) v += resid[(size_t)m * Nd + n];
      out[(size_t)m * Nd + n] = v;
    }
  }
}

// ---------------- Prepass: split K (kv cols 0..1023) into bf16 hi/lo -------
// Output layout: [b*16+h][t][64]
__global__ __launch_bounds__(256) void splitk_k(const float* __restrict__ kvf,
                                                unsigned short* __restrict__ khi,
                                                unsigned short* __restrict__ klo) {
  size_t idx = (size_t)blockIdx.x * 256 + threadIdx.x;  // one float4 each
  int tok = (int)(idx >> 8);
  int c = (int)(idx & 255) * 4;
  float4 v = *(const float4*)(kvf + (size_t)tok * (2 * CDIM) + c);
  int hh = c >> 6, d = c & 63;
  int b = tok >> 11, tt = tok & (TLEN - 1);
  size_t dst = ((size_t)(b * NHEAD + hh) * TLEN + tt) * HDIM + d;
  float a[4]; f4a(v, a);
  ushort4 hi, lo;
  unsigned short* hp = (unsigned short*)&hi;
  unsigned short* lp = (unsigned short*)&lo;
#pragma unroll
  for (int u = 0; u < 4; u++) {
    hp[u] = f2bf(a[u]);
    lp[u] = f2bf(a[u] - bf2f(hp[u]));
  }
  *(ushort4*)(khi + dst) = hi;
  *(ushort4*)(klo + dst) = lo;
}

// ---------------- Prepass: transpose+split V into bf16 hi/lo ---------------
// Output layout: [b*16+h][d(64)][t(2048)]
__global__ __launch_bounds__(256) void vtsplit_k(const float* __restrict__ kvf,
                                                 unsigned short* __restrict__ vthi,
                                                 unsigned short* __restrict__ vtlo) {
  int t0 = blockIdx.x * 64;
  int bh = blockIdx.y;
  int b = bh >> 4, hh = bh & 15;
  __shared__ float tile[64][65];
  int t = threadIdx.x;
  int r = t >> 2, c0 = (t & 3) * 16;
  const float* src = kvf + ((size_t)b * TLEN + t0 + r) * (2 * CDIM) + CDIM + hh * HDIM + c0;
#pragma unroll
  for (int u = 0; u < 4; u++) {
    float4 v = *(const float4*)(src + u * 4);
    tile[r][c0 + u * 4 + 0] = v.x; tile[r][c0 + u * 4 + 1] = v.y;
    tile[r][c0 + u * 4 + 2] = v.z; tile[r][c0 + u * 4 + 3] = v.w;
  }
  __syncthreads();
  int d = t >> 2, cc0 = (t & 3) * 16;
  __attribute__((aligned(16))) unsigned short th[16], tl[16];
#pragma unroll
  for (int u = 0; u < 16; u++) {
    float f = tile[cc0 + u][d];
    th[u] = f2bf(f);
    tl[u] = f2bf(f - bf2f(th[u]));
  }
  unsigned short* dh = vthi + ((size_t)bh * HDIM + d) * TLEN + t0 + cc0;
  unsigned short* dl = vtlo + ((size_t)bh * HDIM + d) * TLEN + t0 + cc0;
  *(uint4*)dh = *(const uint4*)th; *(uint4*)(dh + 8) = *(const uint4*)(th + 8);
  *(uint4*)dl = *(const uint4*)tl; *(uint4*)(dl + 8) = *(const uint4*)(tl + 8);
}

// ---------------- Flash attention, split-bf16 MFMA (fp32-grade accuracy) ---
// Per block: 64 q-rows, one (h,b). 4 waves x 16 q-rows. K tiles of 64.
// QK^T: S = Qhi*Khi + Qhi*Klo + Qlo*Khi (lo*lo dropped, ~2^-18 rel).
// PV:   O += Phi*Vhi + Phi*Vlo + Plo*Vhi.
// Staging reuses the harness-verified gload_lds16 + XOR-swizzle pattern.
__global__ __launch_bounds__(256) void attn_mfma_k(
    const float* __restrict__ qf,
    const unsigned short* __restrict__ khi, const unsigned short* __restrict__ klo,
    const unsigned short* __restrict__ vthi, const unsigned short* __restrict__ vtlo,
    float* __restrict__ y) {
  int qt = blockIdx.x, h = blockIdx.y, b = blockIdx.z;
  int bh = b * NHEAD + h;
  __shared__ __attribute__((aligned(16))) unsigned short Khs[64 * 64];
  __shared__ __attribute__((aligned(16))) unsigned short Kls[64 * 64];
  __shared__ __attribute__((aligned(16))) unsigned short Vhs[64 * 64];
  __shared__ __attribute__((aligned(16))) unsigned short Vls[64 * 64];
  __shared__ __attribute__((aligned(16))) unsigned short Phs[4 * 16 * 64];
  __shared__ __attribute__((aligned(16))) unsigned short Pls[4 * 16 * 64];
  int t = threadIdx.x, w = t >> 6, l = t & 63;
  int l16 = l & 15, lg = l >> 4;
  int wq = w * 16;
  int srow = t >> 3, sslot = t & 7;
  // ---- Q fragments: fp32 load, scale 1/8 (exact), split hi/lo in-register
  bf16x8 aQh[2], aQl[2];
  {
    size_t qrow = (size_t)b * TLEN + qt * 64 + wq + l16;
#pragma unroll
    for (int ks = 0; ks < 2; ks++) {
      const float* qp = qf + qrow * CDIM + h * HDIM + ks * 32 + lg * 8;
      float4 v0 = *(const float4*)qp;
      float4 v1 = *(const float4*)(qp + 4);
      float vv[8] = {v0.x, v0.y, v0.z, v0.w, v1.x, v1.y, v1.z, v1.w};
#pragma unroll
      for (int u = 0; u < 8; u++) {
        float s = vv[u] * 0.125f;
        unsigned short hi = f2bf(s);
        aQh[ks][u] = (short)hi;
        aQl[ks][u] = (short)f2bf(s - bf2f(hi));
      }
    }
  }
  float m_i[4], l_i[4];
  f32x4 oAcc[4] = {};
#pragma unroll
  for (int r = 0; r < 4; r++) { m_i[r] = -1e30f; l_i[r] = 0.f; }
  float slope = (float)(h + 1) * (1.0f / NHEAD);
  unsigned short* Ph = Phs + w * 1024;
  unsigned short* Pl = Pls + w * 1024;
  int qg0 = qt * 64 + wq + lg * 4;  // + r
  for (int kt = 0; kt <= qt; kt++) {
    __syncthreads();
#pragma unroll
    for (int i = 0; i < 2; i++) {
      int r = i * 32 + srow;
      int sl = sslot ^ (r & 7);
      size_t krow = (size_t)bh * TLEN + kt * 64 + r;
      gload_lds16(khi + krow * HDIM + sl * 8, Khs + i * 2048 + w * 512);
      gload_lds16(klo + krow * HDIM + sl * 8, Kls + i * 2048 + w * 512);
      size_t vrow = (size_t)bh * HDIM + r;
      gload_lds16(vthi + vrow * TLEN + kt * 64 + sl * 8, Vhs + i * 2048 + w * 512);
      gload_lds16(vtlo + vrow * TLEN + kt * 64 + sl * 8, Vls + i * 2048 + w * 512);
    }
    __syncthreads();
    // ---- QK^T (3-term split)
    f32x4 sAcc[4] = {};
#pragma unroll
    for (int ks = 0; ks < 2; ks++) {
#pragma unroll
      for (int bn = 0; bn < 4; bn++) {
        int br = bn * 16 + l16;
        int off = br * 64 + (((ks * 4 + lg) ^ (br & 7)) << 3);
        bf16x8 kh = *(const bf16x8*)&Khs[off];
        bf16x8 kl = *(const bf16x8*)&Kls[off];
        sAcc[bn] = __builtin_amdgcn_mfma_f32_16x16x32_bf16(aQl[ks], kh, sAcc[bn], 0, 0, 0);
        sAcc[bn] = __builtin_amdgcn_mfma_f32_16x16x32_bf16(aQh[ks], kl, sAcc[bn], 0, 0, 0);
        sAcc[bn] = __builtin_amdgcn_mfma_f32_16x16x32_bf16(aQh[ks], kh, sAcc[bn], 0, 0, 0);
      }
    }
    // ---- ALiBi + causal mask + online softmax
    // C layout: element (bn, r) -> row q = lg*4+r, col k = bn*16+l16
    int kg0 = kt * 64 + l16;
    float alpha[4];
    float pv[4][4];
#pragma unroll
    for (int r = 0; r < 4; r++) {
      int qg = qg0 + r;
      float mx = -1e30f;
#pragma unroll
      for (int bn = 0; bn < 4; bn++) {
        int kg = kg0 + bn * 16;
        float s = sAcc[bn][r] + slope * (float)(kg - qg);
        s = (kg <= qg) ? s : -1e30f;
        pv[r][bn] = s;
        mx = fmaxf(mx, s);
      }
#pragma unroll
      for (int off = 1; off < 16; off <<= 1) mx = fmaxf(mx, __shfl_xor(mx, off));
      float newm = fmaxf(m_i[r], mx);
      alpha[r] = __expf(m_i[r] - newm);
      m_i[r] = newm;
      float rs = 0.f;
#pragma unroll
      for (int bn = 0; bn < 4; bn++) {
        float p = __expf(pv[r][bn] - newm);
        pv[r][bn] = p;
        rs += p;
      }
#pragma unroll
      for (int off = 1; off < 16; off <<= 1) rs += __shfl_xor(rs, off);
      l_i[r] = l_i[r] * alpha[r] + rs;
#pragma unroll
      for (int dn = 0; dn < 4; dn++) oAcc[dn][r] *= alpha[r];
    }
    // ---- write P hi/lo to per-wave swizzled LDS tile [16][64]
#pragma unroll
    for (int r = 0; r < 4; r++) {
      int qloc = lg * 4 + r;
#pragma unroll
      for (int bn = 0; bn < 4; bn++) {
        int kloc = bn * 16 + l16;
        int addr = qloc * 64 + (((kloc >> 3) ^ (qloc & 7)) << 3) + (kloc & 7);
        float p = pv[r][bn];
        unsigned short hi = f2bf(p);
        Ph[addr] = hi;
        Pl[addr] = f2bf(p - bf2f(hi));
      }
    }
    // ---- PV (3-term split); wave-private P, no barrier needed
#pragma unroll
    for (int ks = 0; ks < 2; ks++) {
      int aoff = l16 * 64 + (((ks * 4 + lg) ^ (l16 & 7)) << 3);
      bf16x8 ph = *(const bf16x8*)&Ph[aoff];
      bf16x8 pl = *(const bf16x8*)&Pl[aoff];
#pragma unroll
      for (int dn = 0; dn < 4; dn++) {
        int br = dn * 16 + l16;
        int off = br * 64 + (((ks * 4 + lg) ^ (br & 7)) << 3);
        bf16x8 vh = *(const bf16x8*)&Vhs[off];
        bf16x8 vl = *(const bf16x8*)&Vls[off];
        oAcc[dn] = __builtin_amdgcn_mfma_f32_16x16x32_bf16(pl, vh, oAcc[dn], 0, 0, 0);
        oAcc[dn] = __builtin_amdgcn_mfma_f32_16x16x32_bf16(ph, vl, oAcc[dn], 0, 0, 0);
        oAcc[dn] = __builtin_amdgcn_mfma_f32_16x16x32_bf16(ph, vh, oAcc[dn], 0, 0, 0);
      }
    }
  }
  // ---- epilogue: y fp32
#pragma unroll
  for (int r = 0; r < 4; r++) {
    float invl = 1.0f / l_i[r];
    size_t row = (size_t)b * TLEN + qt * 64 + wq + lg * 4 + r;
#pragma unroll
    for (int dn = 0; dn < 4; dn++)
      y[row * CDIM + h * HDIM + dn * 16 + l16] = oAcc[dn][r] * invl;
  }
}

// ---------------- Router: fp32 rmsnorm + logits from post-attn residual ----
__global__ void zero_cnt_k(int* cnt) {
  if (threadIdx.x < NEXP) cnt[threadIdx.x] = 0;
}

__global__ __launch_bounds__(64) void router_k(const float* __restrict__ xr,
                                               const float* __restrict__ fnw,
                                               const float* __restrict__ rw,
                                               int* __restrict__ sel_idx,
                                               float* __restrict__ sel_w,
                                               int* __restrict__ cnt) {
  int tok = blockIdx.x;
  int lane = threadIdx.x;  // 64
  const float* row = xr + (size_t)tok * CDIM;
  float4 v[4];
  float ss = 0.f;
#pragma unroll
  for (int u = 0; u < 4; u++) {
    v[u] = ((const float4*)row)[lane + 64 * u];
    ss += v[u].x * v[u].x + v[u].y * v[u].y + v[u].z * v[u].z + v[u].w * v[u].w;
  }
#pragma unroll
  for (int off = 32; off > 0; off >>= 1) ss += __shfl_xor(ss, off);
  float inv = rsqrtf(ss * (1.0f / CDIM) + 1e-8f);
  float acc[NEXP] = {};
#pragma unroll
  for (int u = 0; u < 4; u++) {
    int c0 = (lane + 64 * u) * 4;
    float hv[4];
    f4a(v[u], hv);
#pragma unroll
    for (int j = 0; j < 4; j++) {
      float h = hv[j] * inv * fnw[c0 + j];
      const float* r = rw + (size_t)(c0 + j) * NEXP;
#pragma unroll
      for (int e = 0; e < NEXP; e++) acc[e] += h * r[e];
    }
  }
#pragma unroll
  for (int e = 0; e < NEXP; e++)
#pragma unroll
    for (int off = 32; off > 0; off >>= 1) acc[e] += __shfl_xor(acc[e], off);
  if (lane == 0) {
    int i0 = 0; float l0 = acc[0];
    for (int e = 1; e < NEXP; e++) if (acc[e] > l0) { l0 = acc[e]; i0 = e; }
    int i1 = -1; float l1 = -1e30f;
    for (int e = 0; e < NEXP; e++)
      if (e != i0 && acc[e] > l1) { l1 = acc[e]; i1 = e; }
    float w0 = 1.f / (1.f + __expf(l1 - l0));
    sel_idx[2 * tok] = i0; sel_idx[2 * tok + 1] = i1;
    sel_w[2 * tok] = w0;   sel_w[2 * tok + 1] = 1.f - w0;
    atomicAdd(&cnt[i0], 1);
    atomicAdd(&cnt[i1], 1);
  }
}

__global__ void scan_k(const int* __restrict__ cnt, int* __restrict__ eoff,
                       int* __restrict__ cursor) {
  if (threadIdx.x == 0) {
    int s = 0;
    for (int e = 0; e < NEXP; e++) { eoff[e] = s; cursor[e] = s; s += cnt[e]; }
    eoff[NEXP] = s;
  }
}

__global__ __launch_bounds__(256) void gather_k(const int* __restrict__ sel_idx,
                                                const float* __restrict__ sel_w,
                                                int* __restrict__ cursor,
                                                int* __restrict__ gtok,
                                                float* __restrict__ gwv) {
  int t = blockIdx.x * blockDim.x + threadIdx.x;
  if (t >= NTOK) return;
#pragma unroll
  for (int k = 0; k < 2; k++) {
    int e = sel_idx[2 * t + k];
    int p = atomicAdd(&cursor[e], 1);
    gtok[p] = t;
    gwv[p] = sel_w[2 * t + k];
  }
}

// ---------------- MoE GEMM1 (MFMA): mid = bf16( silu(h2@gate) * (h2@up) ) --
__global__ __launch_bounds__(256) void moe_g1_k(
    const unsigned short* __restrict__ h2b, const unsigned short* __restrict__ gT,
    const unsigned short* __restrict__ uT, const int* __restrict__ cnt,
    const int* __restrict__ eoff, const int* __restrict__ gtok,
    unsigned short* __restrict__ mid) {
  int e = blockIdx.z, rt = blockIdx.y, ht = blockIdx.x;
  int ne = cnt[e];
  if (rt * 128 >= ne) return;
  int base = eoff[e];
  __shared__ __attribute__((aligned(16))) unsigned short As[128 * 64];
  __shared__ __attribute__((aligned(16))) unsigned short B1s[128 * 64];
  __shared__ __attribute__((aligned(16))) unsigned short B2s[128 * 64];
  __shared__ int toks[128];
  int t = threadIdx.x;
  if (t < 128) {
    int r = rt * 128 + t;
    toks[t] = (r < ne) ? gtok[base + r] : 0;  // pad rows read row 0 (discarded)
  }
  __syncthreads();
  int w = t >> 6, l = t & 63, l16 = l & 15, lg = l >> 4;
  int wm = (w >> 1) * 64, wn = (w & 1) * 64;
  int srow = t >> 3, sslot = t & 7;
  const unsigned short* G = gT + (size_t)e * CDIM * HID;  // [HID][CDIM]
  const unsigned short* U = uT + (size_t)e * CDIM * HID;
  int n0 = ht * 128;
  int arows[4];
#pragma unroll
  for (int i = 0; i < 4; i++) arows[i] = toks[i * 32 + srow];
  f32x4 acc1[4][4] = {}, acc2[4][4] = {};
  for (int k0 = 0; k0 < CDIM; k0 += 64) {
    __syncthreads();
#pragma unroll
    for (int i = 0; i < 4; i++) {
      int r = i * 32 + srow;
      int sl = sslot ^ (r & 7);
      gload_lds16(h2b + (size_t)arows[i] * CDIM + k0 + sl * 8, As + i * 2048 + w * 512);
      gload_lds16(G + (size_t)(n0 + r) * CDIM + k0 + sl * 8, B1s + i * 2048 + w * 512);
      gload_lds16(U + (size_t)(n0 + r) * CDIM + k0 + sl * 8, B2s + i * 2048 + w * 512);
    }
    __syncthreads();
#pragma unroll
    for (int ks = 0; ks < 2; ks++) {
      bf16x8 af[4], b1[4], b2[4];
#pragma unroll
      for (int x = 0; x < 4; x++) {
        int ar = wm + x * 16 + l16;
        int br = wn + x * 16 + l16;
        int aof = ar * 64 + (((ks * 4 + lg) ^ (ar & 7)) << 3);
        int bof = br * 64 + (((ks * 4 + lg) ^ (br & 7)) << 3);
        af[x] = *(const bf16x8*)&As[aof];
        b1[x] = *(const bf16x8*)&B1s[bof];
        b2[x] = *(const bf16x8*)&B2s[bof];
      }
#pragma unroll
      for (int mi = 0; mi < 4; mi++)
#pragma unroll
        for (int nj = 0; nj < 4; nj++) {
          acc1[mi][nj] = __builtin_amdgcn_mfma_f32_16x16x32_bf16(af[mi], b1[nj], acc1[mi][nj], 0, 0, 0);
          acc2[mi][nj] = __builtin_amdgcn_mfma_f32_16x16x32_bf16(af[mi], b2[nj], acc2[mi][nj], 0, 0, 0);
        }
    }
  }
#pragma unroll
  for (int mi = 0; mi < 4; mi++)
#pragma unroll
    for (int rr = 0; rr < 4; rr++) {
      int rloc = wm + mi * 16 + lg * 4 + rr;
      int r = rt * 128 + rloc;
      if (r < ne) {
        size_t slot = (size_t)base + r;
#pragma unroll
        for (int nj = 0; nj < 4; nj++) {
          float g = acc1[mi][nj][rr], u = acc2[mi][nj][rr];
          float val = g / (1.f + __expf(-g)) * u;  // silu(g)*u
          mid[slot * HID + n0 + wn + nj * 16 + l16] = f2bf(val);
        }
      }
    }
}

// ---------------- MoE GEMM2 (MFMA): out += w * (mid @ down_e) --------------
__global__ __launch_bounds__(256) void moe_g2_k(
    const unsigned short* __restrict__ mid, const unsigned short* __restrict__ dT,
    const int* __restrict__ cnt, const int* __restrict__ eoff,
    const int* __restrict__ gtok, const float* __restrict__ gwv,
    float* __restrict__ out) {
  int e = blockIdx.z, rt = blockIdx.y, ct = blockIdx.x;
  int ne = cnt[e];
  if (rt * 128 >= ne) return;
  int base = eoff[e];
  __shared__ __attribute__((aligned(16))) unsigned short As[128 * 64];
  __shared__ __attribute__((aligned(16))) unsigned short Bs[128 * 64];
  int t = threadIdx.x;
  int w = t >> 6, l = t & 63, l16 = l & 15, lg = l >> 4;
  int wm = (w >> 1) * 64, wn = (w & 1) * 64;
  int srow = t >> 3, sslot = t & 7;
  const unsigned short* D = dT + (size_t)e * HID * CDIM;  // [CDIM][HID]
  int n0 = ct * 128;
  int aslots[4];
#pragma unroll
  for (int i = 0; i < 4; i++) {
    int sidx = base + rt * 128 + i * 32 + srow;
    aslots[i] = (sidx < NSLOT) ? sidx : (NSLOT - 1);  // pad rows discarded
  }
  f32x4 acc[4][4] = {};
  for (int k0 = 0; k0 < HID; k0 += 64) {
    __syncthreads();
#pragma unroll
    for (int i = 0; i < 4; i++) {
      int r = i * 32 + srow;
      int sl = sslot ^ (r & 7);
      gload_lds16(mid + (size_t)aslots[i] * HID + k0 + sl * 8, As + i * 2048 + w * 512);
      gload_lds16(D + (size_t)(n0 + r) * HID + k0 + sl * 8, Bs + i * 2048 + w * 512);
    }
    __syncthreads();
#pragma unroll
    for (int ks = 0; ks < 2; ks++) {
      bf16x8 af[4], bfr[4];
#pragma unroll
      for (int x = 0; x < 4; x++) {
        int ar = wm + x * 16 + l16;
        int br = wn + x * 16 + l16;
        af[x]  = *(const bf16x8*)&As[ar * 64 + (((ks * 4 + lg) ^ (ar & 7)) << 3)];
        bfr[x] = *(const bf16x8*)&Bs[br * 64 + (((ks * 4 + lg) ^ (br & 7)) << 3)];
      }
#pragma unroll
      for (int mi = 0; mi < 4; mi++)
#pragma unroll
        for (int nj = 0; nj < 4; nj++)
          acc[mi][nj] = __builtin_amdgcn_mfma_f32_16x16x32_bf16(af[mi], bfr[nj], acc[mi][nj], 0, 0, 0);
    }
  }
#pragma unroll
  for (int mi = 0; mi < 4; mi++)
#pragma unroll
    for (int rr = 0; rr < 4; rr++) {
      int r = rt * 128 + wm + mi * 16 + lg * 4 + rr;
      if (r < ne) {
        int tok = gtok[base + r];
        float wv = gwv[base + r];
#pragma unroll
        for (int nj = 0; nj < 4; nj++)
          atomicAdd(&out[(size_t)tok * CDIM + n0 + wn + nj * 16 + l16],
                    wv * acc[mi][nj][rr]);
      }
    }
}

// ---------------------------------------------------------------------------
extern "C" void kernel_launch(void* const* d_in, const int* in_sizes, int n_in,
                              void* d_out, int out_size, void* d_ws, size_t ws_size,
                              hipStream_t stream) {
  (void)in_sizes; (void)n_in; (void)out_size; (void)ws_size;
  const float* x   = (const float*)d_in[0];
  const float* anw = (const float*)d_in[1];
  const float* fnw = (const float*)d_in[2];
  const float* qw  = (const float*)d_in[3];
  const float* qb  = (const float*)d_in[4];
  const float* kvw = (const float*)d_in[5];
  const float* kvb = (const float*)d_in[6];
  const float* ow  = (const float*)d_in[7];
  const float* ob  = (const float*)d_in[8];
  const float* rw  = (const float*)d_in[9];
  const float* gw  = (const float*)d_in[10];
  const float* uw  = (const float*)d_in[11];
  const float* dw  = (const float*)d_in[12];
  float* out = (float*)d_out;

  // Workspace layout (265 MiB, same total as proven r3):
  //   [0,1M)     meta: sel_idx/sel_w/cnt/gtok/gwv
  //   [1M,17M)   h1f f32 (rmsnorm->kvGEMM), THEN khi/klo bf16 (splitk->attn)
  //   [17M,33M)  qf f32 (live through attn: Q frags read directly)
  //   [33M,65M)  kvf f32 (dead after vtsplit); yf f32 aliases [33M,49M)
  //   [65M,81M)  vthi/vtlo bf16 (attn); h2b bf16 aliases [65M,73M) post-attn
  //   [73M,137M) gT  bf16 [8][4096][1024]  } converted AFTER attn
  //   [137M,201M) uT bf16                  } (region free during attn)
  //   [201M,265M) dT bf16 [8][1024][4096]
  //   mid bf16 [8192][4096] aliases [1M,65M) (all attn bufs dead pre-MoE)
  char* ws = (char*)d_ws;
  int*   sel_idx = (int*)(ws);
  float* sel_w   = (float*)(ws + (32 << 10));
  int*   cnt     = (int*)(ws + (64 << 10));
  int*   eoff    = cnt + 16;
  int*   cursor  = cnt + 32;
  int*   gtok    = (int*)(ws + (96 << 10));
  float* gwv     = (float*)(ws + (128 << 10));
  float* h1f = (float*)(ws + ((size_t)1 << 20));
  unsigned short* khi = (unsigned short*)(ws + ((size_t)1 << 20));
  unsigned short* klo = (unsigned short*)(ws + ((size_t)9 << 20));
  float* qf  = (float*)(ws + ((size_t)17 << 20));
  float* kvf = (float*)(ws + ((size_t)33 << 20));
  float* yf  = (float*)(ws + ((size_t)33 << 20));  // alias: kvf dead pre-attn
  unsigned short* vthi = (unsigned short*)(ws + ((size_t)65 << 20));
  unsigned short* vtlo = (unsigned short*)(ws + ((size_t)73 << 20));
  unsigned short* mid = (unsigned short*)(ws + ((size_t)1 << 20));
  unsigned short* h2b = (unsigned short*)(ws + ((size_t)65 << 20));  // post-attn
  unsigned short* gT = (unsigned short*)(ws + ((size_t)73 << 20));   // post-attn
  unsigned short* uT = (unsigned short*)(ws + ((size_t)137 << 20));
  unsigned short* dT = (unsigned short*)(ws + ((size_t)201 << 20));

  zero_cnt_k<<<1, 64, 0, stream>>>(cnt);
  // h1 = rmsnorm(x) (fp32)
  rmsnorm_f32_k<<<NTOK, 256, 0, stream>>>(x, anw, h1f);
  // q = h1@qw + qb ; kv = h1@kvw + kvb   (fp32)
  gemm_bias_k<<<dim3(16, 64), 256, 0, stream>>>(h1f, qw, qb, nullptr, qf, CDIM, CDIM);
  gemm_bias_k<<<dim3(32, 64), 256, 0, stream>>>(h1f, kvw, kvb, nullptr, kvf, CDIM, 2 * CDIM);
  // split K and transpose+split V to bf16 hi/lo panels (h1f dead -> khi/klo)
  splitk_k<<<NTOK * CDIM / 4 / 256, 256, 0, stream>>>(kvf, khi, klo);
  vtsplit_k<<<dim3(TLEN / 64, BATCH * NHEAD), 256, 0, stream>>>(kvf, vthi, vtlo);
  // y = attention (split-bf16 MFMA, fp32-grade accuracy; yf aliases dead kvf)
  attn_mfma_k<<<dim3(TLEN / 64, NHEAD, BATCH), 256, 0, stream>>>(qf, khi, klo, vthi, vtlo, yf);
  // out = x + y@ow + ob  (fp32)
  gemm_bias_k<<<dim3(16, 64), 256, 0, stream>>>(yf, ow, ob, x, out, CDIM, CDIM);
  // MoE weight convert+transpose (after attn: region was holding vt splits)
  convT_k<<<dim3(64, 16, NEXP), 256, 0, stream>>>(gw, gT, CDIM, HID);
  convT_k<<<dim3(64, 16, NEXP), 256, 0, stream>>>(uw, uT, CDIM, HID);
  convT_k<<<dim3(16, 64, NEXP), 256, 0, stream>>>(dw, dT, HID, CDIM);
  // h2 = rmsnorm(out) (bf16, MoE A-operand)
  rmsnorm_bf16_k<<<NTOK, 256, 0, stream>>>(out, fnw, h2b);
  // routing: fp32-exact logits from post-attn residual
  router_k<<<NTOK, 64, 0, stream>>>(out, fnw, rw, sel_idx, sel_w, cnt);
  scan_k<<<1, 64, 0, stream>>>(cnt, eoff, cursor);
  gather_k<<<16, 256, 0, stream>>>(sel_idx, sel_w, cursor, gtok, gwv);
  // MoE (bf16 MFMA — post-routing, continuous error only)
  moe_g1_k<<<dim3(HID / 128, 64, NEXP), 256, 0, stream>>>(h2b, gT, uT, cnt, eoff, gtok, mid);
  moe_g2_k<<<dim3(CDIM / 128, 64, NEXP), 256, 0, stream>>>(mid, dT, cnt, eoff, gtok, gwv, out);
}